// Round 1
// baseline (2565.716 us; speedup 1.0000x reference)
//
#include <hip/hip_runtime.h>
#include <cstddef>
#include <cstdint>

static constexpr int B   = 4;
static constexpr int L   = 4096;
static constexpr int D   = 1024;
static constexpr int M   = B * L;      // 16384 rows
static constexpr int NCH = 64;         // scan chunks along L
static constexpr int CHL = L / NCH;    // 64 rows per chunk

// ---------------- device helpers ----------------
__device__ __forceinline__ float4 qmul(const float4 a, const float4 b) {
    float4 r;
    r.x = a.x * b.x - a.y * b.y - a.z * b.z - a.w * b.w;
    r.y = a.x * b.y + a.y * b.x + a.z * b.w - a.w * b.z;
    r.z = a.x * b.z - a.y * b.w + a.z * b.x + a.w * b.y;
    r.w = a.x * b.w + a.y * b.z - a.z * b.y + a.w * b.x;
    return r;
}
__device__ __forceinline__ float4 qconj(const float4 a) {
    return make_float4(a.x, -a.y, -a.z, -a.w);
}
__device__ __forceinline__ float4 qnorm(const float4 a) {
    float n = sqrtf(a.x * a.x + a.y * a.y + a.z * a.z + a.w * a.w);
    float inv = 1.0f / fmaxf(n, 1e-12f);
    return make_float4(a.x * inv, a.y * inv, a.z * inv, a.w * inv);
}
__device__ __forceinline__ float gelu_exact(float v) {
    return 0.5f * v * (1.0f + erff(v * 0.7071067811865476f));
}

// ---------------- GEMM: C[M,N] = epi(A[M,K] @ W[K,N] + bias) ----------------
// EPI: 0 = bias, 1 = bias+gelu(exact), 2 = bias + residual
template <int EPI>
__global__ __launch_bounds__(256)
void gemm_k(const float* __restrict__ A, const float* __restrict__ W,
            const float* __restrict__ bias, const float* __restrict__ resid,
            float* __restrict__ C, int Mm, int Nn, int Kk)
{
    constexpr int BM = 128, BN = 128, BK = 16, PAD = 4;
    __shared__ float As[BK][BM + PAD];   // transposed: As[k][m]
    __shared__ float Bs[BK][BN + PAD];   // natural:    Bs[k][n]

    const int tid = threadIdx.x;
    const int tx  = tid & 15;            // 0..15 -> 8 cols each
    const int ty  = tid >> 4;            // 0..15 -> 8 rows each
    const int m0  = blockIdx.y * BM;
    const int n0  = blockIdx.x * BN;

    const int ar = tid >> 1;             // 0..127  (A tile row)
    const int ac = (tid & 1) * 8;        // 0 or 8  (A tile k-start)
    const int br = tid >> 4;             // 0..15   (B tile k row)
    const int bc = (tid & 15) * 8;       // 0..120  (B tile n-start)

    float acc[8][8] = {};

    for (int k0 = 0; k0 < Kk; k0 += BK) {
        const float4 a0 = *reinterpret_cast<const float4*>(&A[(size_t)(m0 + ar) * Kk + k0 + ac]);
        const float4 a1 = *reinterpret_cast<const float4*>(&A[(size_t)(m0 + ar) * Kk + k0 + ac + 4]);
        const float4 b0 = *reinterpret_cast<const float4*>(&W[(size_t)(k0 + br) * Nn + n0 + bc]);
        const float4 b1 = *reinterpret_cast<const float4*>(&W[(size_t)(k0 + br) * Nn + n0 + bc + 4]);
        As[ac + 0][ar] = a0.x; As[ac + 1][ar] = a0.y; As[ac + 2][ar] = a0.z; As[ac + 3][ar] = a0.w;
        As[ac + 4][ar] = a1.x; As[ac + 5][ar] = a1.y; As[ac + 6][ar] = a1.z; As[ac + 7][ar] = a1.w;
        *reinterpret_cast<float4*>(&Bs[br][bc])     = b0;
        *reinterpret_cast<float4*>(&Bs[br][bc + 4]) = b1;
        __syncthreads();

        #pragma unroll
        for (int kk = 0; kk < BK; ++kk) {
            float a[8], b[8];
            *reinterpret_cast<float4*>(&a[0]) = *reinterpret_cast<const float4*>(&As[kk][ty * 8]);
            *reinterpret_cast<float4*>(&a[4]) = *reinterpret_cast<const float4*>(&As[kk][ty * 8 + 4]);
            *reinterpret_cast<float4*>(&b[0]) = *reinterpret_cast<const float4*>(&Bs[kk][tx * 8]);
            *reinterpret_cast<float4*>(&b[4]) = *reinterpret_cast<const float4*>(&Bs[kk][tx * 8 + 4]);
            #pragma unroll
            for (int i = 0; i < 8; ++i)
                #pragma unroll
                for (int j = 0; j < 8; ++j)
                    acc[i][j] = fmaf(a[i], b[j], acc[i][j]);
        }
        __syncthreads();
    }

    float bb[8];
    *reinterpret_cast<float4*>(&bb[0]) = *reinterpret_cast<const float4*>(&bias[n0 + tx * 8]);
    *reinterpret_cast<float4*>(&bb[4]) = *reinterpret_cast<const float4*>(&bias[n0 + tx * 8 + 4]);

    #pragma unroll
    for (int i = 0; i < 8; ++i) {
        const int m = m0 + ty * 8 + i;
        float o[8];
        #pragma unroll
        for (int j = 0; j < 8; ++j) {
            float v = acc[i][j] + bb[j];
            if (EPI == 1) v = gelu_exact(v);
            o[j] = v;
        }
        if (EPI == 2) {
            const float4 r0 = *reinterpret_cast<const float4*>(&resid[(size_t)m * Nn + n0 + tx * 8]);
            const float4 r1 = *reinterpret_cast<const float4*>(&resid[(size_t)m * Nn + n0 + tx * 8 + 4]);
            o[0] += r0.x; o[1] += r0.y; o[2] += r0.z; o[3] += r0.w;
            o[4] += r1.x; o[5] += r1.y; o[6] += r1.z; o[7] += r1.w;
        }
        *reinterpret_cast<float4*>(&C[(size_t)m * Nn + n0 + tx * 8])     = *reinterpret_cast<float4*>(&o[0]);
        *reinterpret_cast<float4*>(&C[(size_t)m * Nn + n0 + tx * 8 + 4]) = *reinterpret_cast<float4*>(&o[4]);
    }
}

// ---------------- rotated = quat_rotate(normalize(kraw), value) ----------------
__global__ __launch_bounds__(256)
void rotate_fwd_k(const float* __restrict__ kraw, const float* __restrict__ val,
                  float* __restrict__ out, int nq)
{
    const int i = blockIdx.x * 256 + threadIdx.x;
    if (i >= nq) return;
    const float4 q = qnorm(*reinterpret_cast<const float4*>(kraw + (size_t)i * 4));
    const float4 v = *reinterpret_cast<const float4*>(val + (size_t)i * 4);
    const float4 r = qmul(qmul(q, v), qconj(q));
    *reinterpret_cast<float4*>(out + (size_t)i * 4) = r;
}

// ---------------- blocked cumsum along L (axis=1), per (b,d) column ----------------
// g-layout for pass1/3: g = b*65536 + ch*1024 + d  (d fastest -> coalesced)
__global__ __launch_bounds__(256)
void scan_pass1(const float* __restrict__ rot, float* __restrict__ part)
{
    const int g  = blockIdx.x * 256 + threadIdx.x;     // 0 .. B*NCH*D-1
    const int d  = g & (D - 1);
    const int ch = (g >> 10) & (NCH - 1);
    const int b  = g >> 16;
    const size_t base = ((size_t)b * L + (size_t)ch * CHL) * D + d;
    float s = 0.f;
    for (int i = 0; i < CHL; ++i) s += rot[base + (size_t)i * D];
    part[g] = s;
}

__global__ __launch_bounds__(256)
void scan_pass2(float* __restrict__ part)
{
    const int g = blockIdx.x * 256 + threadIdx.x;      // 0 .. B*D-1
    const int d = g & (D - 1);
    const int b = g >> 10;
    float run = 0.f;
    for (int c = 0; c < NCH; ++c) {
        const size_t idx = ((size_t)b * NCH + c) * D + d;
        const float t = part[idx];
        part[idx] = run;       // exclusive scan of chunk sums
        run += t;
    }
}

__global__ __launch_bounds__(256)
void scan_pass3(float* __restrict__ rot, const float* __restrict__ part)
{
    const int g  = blockIdx.x * 256 + threadIdx.x;
    const int d  = g & (D - 1);
    const int ch = (g >> 10) & (NCH - 1);
    const int b  = g >> 16;
    const size_t base = ((size_t)b * L + (size_t)ch * CHL) * D + d;
    float run = part[g];
    for (int i = 0; i < CHL; ++i) {
        const size_t idx = base + (size_t)i * D;
        run += rot[idx];
        rot[idx] = run;        // in-place: rotated -> memory
    }
}

// ---------------- retrieved = quat_rotate(conj(norm(qraw)), memory); /sqrt(l+1); LN ----------------
__global__ __launch_bounds__(256)
void retrieve_ln_k(const float* __restrict__ mem, const float* __restrict__ qraw,
                   const float* __restrict__ gamma, const float* __restrict__ beta,
                   float* __restrict__ out)
{
    const int row = blockIdx.x;            // b*L + l
    const int l   = row & (L - 1);
    const int t   = threadIdx.x;           // quat index 0..255
    const size_t base = (size_t)row * D + t * 4;

    const float4 q  = qnorm(*reinterpret_cast<const float4*>(qraw + base));
    const float4 m4 = *reinterpret_cast<const float4*>(mem + base);
    // quat_rotate(conj(q), m) = conj(q) * m * q
    float4 r = qmul(qmul(qconj(q), m4), q);

    const float inv = 1.0f / sqrtf((float)(l + 1));
    r.x *= inv; r.y *= inv; r.z *= inv; r.w *= inv;

    float s  = r.x + r.y + r.z + r.w;
    float ss = r.x * r.x + r.y * r.y + r.z * r.z + r.w * r.w;
    #pragma unroll
    for (int off = 32; off > 0; off >>= 1) {
        s  += __shfl_xor(s, off);
        ss += __shfl_xor(ss, off);
    }
    __shared__ float red[2][4];
    const int wid = t >> 6, lane = t & 63;
    if (lane == 0) { red[0][wid] = s; red[1][wid] = ss; }
    __syncthreads();
    const float sum = red[0][0] + red[0][1] + red[0][2] + red[0][3];
    const float ssq = red[1][0] + red[1][1] + red[1][2] + red[1][3];
    const float mu  = sum * (1.0f / (float)D);
    const float var = ssq * (1.0f / (float)D) - mu * mu;
    const float sc  = rsqrtf(var + 1e-5f);

    const float4 g4 = *reinterpret_cast<const float4*>(gamma + t * 4);
    const float4 b4 = *reinterpret_cast<const float4*>(beta  + t * 4);
    float4 o;
    o.x = (r.x - mu) * sc * g4.x + b4.x;
    o.y = (r.y - mu) * sc * g4.y + b4.y;
    o.z = (r.z - mu) * sc * g4.z + b4.z;
    o.w = (r.w - mu) * sc * g4.w + b4.w;
    *reinterpret_cast<float4*>(out + base) = o;
}

// ---------------- launch ----------------
extern "C" void kernel_launch(void* const* d_in, const int* in_sizes, int n_in,
                              void* d_out, int out_size, void* d_ws, size_t ws_size,
                              hipStream_t stream)
{
    const float* x     = (const float*)d_in[0];
    const float* Wk1   = (const float*)d_in[1];
    const float* bk1   = (const float*)d_in[2];
    const float* Wk2   = (const float*)d_in[3];
    const float* bk2   = (const float*)d_in[4];
    const float* Wq1   = (const float*)d_in[5];
    const float* bq1   = (const float*)d_in[6];
    const float* Wq2   = (const float*)d_in[7];
    const float* bq2   = (const float*)d_in[8];
    const float* Wv    = (const float*)d_in[9];
    const float* bv    = (const float*)d_in[10];
    const float* gamma = (const float*)d_in[11];
    const float* beta  = (const float*)d_in[12];
    const float* Wo    = (const float*)d_in[13];
    const float* bo    = (const float*)d_in[14];
    float* out = (float*)d_out;

    const size_t tensor = (size_t)M * D;           // 16,777,216 floats (64 MB)
    float* bufA = (float*)d_ws;
    float* bufB = bufA + tensor;
    float* bufC = bufB + tensor;
    float* part = bufC + tensor;                   // B*NCH*D = 262,144 floats (1 MB)

    const dim3 blk(256);
    const dim3 gemmGrid(D / 128, M / 128);         // (8, 128) = 1024 blocks
    const int  nq = B * L * (D / 4);               // 4,194,304 quats

    // K-path first (3 buffers max live)
    gemm_k<1><<<gemmGrid, blk, 0, stream>>>(x,    Wk1, bk1, nullptr, bufA, M, D, D); // hk   -> A
    gemm_k<0><<<gemmGrid, blk, 0, stream>>>(bufA, Wk2, bk2, nullptr, bufB, M, D, D); // kraw -> B
    gemm_k<0><<<gemmGrid, blk, 0, stream>>>(x,    Wv,  bv,  nullptr, bufC, M, D, D); // value-> C

    rotate_fwd_k<<<nq / 256, blk, 0, stream>>>(bufB, bufC, bufA, nq);                // rotated -> A

    scan_pass1<<<(B * NCH * D) / 256, blk, 0, stream>>>(bufA, part);
    scan_pass2<<<(B * D) / 256,       blk, 0, stream>>>(part);
    scan_pass3<<<(B * NCH * D) / 256, blk, 0, stream>>>(bufA, part);                 // memory (in-place A)

    // Q-path
    gemm_k<1><<<gemmGrid, blk, 0, stream>>>(x,    Wq1, bq1, nullptr, bufB, M, D, D); // hq   -> B
    gemm_k<0><<<gemmGrid, blk, 0, stream>>>(bufB, Wq2, bq2, nullptr, bufC, M, D, D); // qraw -> C

    retrieve_ln_k<<<M, blk, 0, stream>>>(bufA, bufC, gamma, beta, bufB);             // ln -> B

    gemm_k<2><<<gemmGrid, blk, 0, stream>>>(bufB, Wo, bo, x, out, M, D, D);          // out = ln@Wo+bo+x
}

// Round 2
// 513.247 us; speedup vs baseline: 4.9990x; 4.9990x over previous
//
#include <hip/hip_runtime.h>
#include <hip/hip_bf16.h>
#include <cstddef>
#include <cstdint>

static constexpr int B   = 4;
static constexpr int L   = 4096;
static constexpr int D   = 1024;
static constexpr int M   = B * L;      // 16384 rows
static constexpr int NCH = 64;         // scan chunks along L
static constexpr int CHL = L / NCH;    // 64 rows per chunk

typedef __attribute__((ext_vector_type(8))) short short8;   // 8 x bf16 (4 VGPRs)
typedef __attribute__((ext_vector_type(4))) float f32x4;

#define AS1C(p) ((const __attribute__((address_space(1))) void*)(p))
#define AS3(p)  ((__attribute__((address_space(3))) void*)(p))

// ---------------- scalar helpers ----------------
__device__ __forceinline__ float b2f(unsigned short u) {
    union { unsigned int i; float f; } c; c.i = ((unsigned int)u) << 16; return c.f;
}
__device__ __forceinline__ unsigned short f2b(float f) {
    union { float f; unsigned int i; } c; c.f = f;
    unsigned int r = c.i + 0x7fffu + ((c.i >> 16) & 1u);
    return (unsigned short)(r >> 16);
}
__device__ __forceinline__ float4 qmul(const float4 a, const float4 b) {
    float4 r;
    r.x = a.x * b.x - a.y * b.y - a.z * b.z - a.w * b.w;
    r.y = a.x * b.y + a.y * b.x + a.z * b.w - a.w * b.z;
    r.z = a.x * b.z - a.y * b.w + a.z * b.x + a.w * b.y;
    r.w = a.x * b.w + a.y * b.z - a.z * b.y + a.w * b.x;
    return r;
}
__device__ __forceinline__ float4 qconj(const float4 a) {
    return make_float4(a.x, -a.y, -a.z, -a.w);
}
__device__ __forceinline__ float4 qnorm(const float4 a) {
    float n = sqrtf(a.x * a.x + a.y * a.y + a.z * a.z + a.w * a.w);
    float inv = 1.0f / fmaxf(n, 1e-12f);
    return make_float4(a.x * inv, a.y * inv, a.z * inv, a.w * inv);
}
__device__ __forceinline__ float gelu_exact(float v) {
    return 0.5f * v * (1.0f + erff(v * 0.7071067811865476f));
}

// ---------------- fp32 -> bf16 convert ----------------
__global__ __launch_bounds__(256)
void conv_k(const float* __restrict__ src, unsigned short* __restrict__ dst, int n4)
{
    const int i = blockIdx.x * 256 + threadIdx.x;
    if (i >= n4) return;
    const float4 v = reinterpret_cast<const float4*>(src)[i];
    ushort4 o;
    o.x = f2b(v.x); o.y = f2b(v.y); o.z = f2b(v.z); o.w = f2b(v.w);
    reinterpret_cast<ushort4*>(dst)[i] = o;
}

// ---------------- W[K,N] fp32 -> W^T[N,K] bf16 ----------------
__global__ __launch_bounds__(256)
void wtrans_k(const float* __restrict__ src, unsigned short* __restrict__ dst)
{
    __shared__ float t[32][33];
    const int tx = threadIdx.x, ty = threadIdx.y;       // 32 x 8
    const int n0 = blockIdx.x * 32, k0 = blockIdx.y * 32;
    #pragma unroll
    for (int j = ty; j < 32; j += 8)
        t[j][tx] = src[(size_t)(k0 + j) * D + n0 + tx];
    __syncthreads();
    #pragma unroll
    for (int j = ty; j < 32; j += 8)
        dst[(size_t)(n0 + j) * D + k0 + tx] = f2b(t[tx][j]);
}

// ---------------- bf16 MFMA GEMM: C = epi(A[M,K] @ B^T[N,K]^T + bias) ----------------
// EPI: 0 = bias -> bf16 | 1 = bias+gelu -> bf16 | 2 = bias -> f32 | 3 = bias+resid -> f32
template <int EPI>
__global__ __launch_bounds__(256)
void gemm_bf16_k(const unsigned short* __restrict__ A,   // [M,K] bf16
                 const unsigned short* __restrict__ BT,  // [N,K] bf16 (W transposed)
                 const float* __restrict__ bias,
                 const float* __restrict__ resid,
                 void* __restrict__ C, int Mm, int Nn, int Kk)
{
    __shared__ alignas(16) unsigned short As[128 * 32];  // [row][k] 8 KB
    __shared__ alignas(16) unsigned short Bs[128 * 32];  // [col][k] 8 KB

    const int tid  = threadIdx.x;
    const int lane = tid & 63;
    const int w    = tid >> 6;          // wave 0..3
    const int wr   = w >> 1;            // wave row 0..1
    const int wc   = w & 1;             // wave col 0..1

    // XCD-aware bijective swizzle (gridDim.x % 8 == 0)
    const int nwg = gridDim.x;
    const int cpx = nwg >> 3;
    const int bid = blockIdx.x;
    const int swz = (bid & 7) * cpx + (bid >> 3);
    const int nTN = Nn >> 7;
    const int m0  = (swz / nTN) << 7;
    const int n0  = (swz % nTN) << 7;

    f32x4 acc[4][4] = {};

    for (int k0 = 0; k0 < Kk; k0 += 32) {
        #pragma unroll
        for (int c = 0; c < 2; ++c) {
            const int i  = (c * 4 + w) * 64 + lane;    // chunk 0..511
            const int r  = i >> 2;                     // tile row 0..127
            const int cc = i & 3;                      // 8-elem k-chunk
            __builtin_amdgcn_global_load_lds(
                AS1C(A + (size_t)(m0 + r) * Kk + k0 + cc * 8),
                AS3((char*)As + (c * 4 + w) * 1024), 16, 0, 0);
            __builtin_amdgcn_global_load_lds(
                AS1C(BT + (size_t)(n0 + r) * Kk + k0 + cc * 8),
                AS3((char*)Bs + (c * 4 + w) * 1024), 16, 0, 0);
        }
        __syncthreads();

        short8 af[4], bf[4];
        #pragma unroll
        for (int mi = 0; mi < 4; ++mi) {
            const int r = wr * 64 + mi * 16 + (lane & 15);
            af[mi] = *reinterpret_cast<const short8*>(
                (const char*)As + r * 64 + (lane >> 4) * 16);
        }
        #pragma unroll
        for (int ni = 0; ni < 4; ++ni) {
            const int cI = wc * 64 + ni * 16 + (lane & 15);
            bf[ni] = *reinterpret_cast<const short8*>(
                (const char*)Bs + cI * 64 + (lane >> 4) * 16);
        }
        #pragma unroll
        for (int mi = 0; mi < 4; ++mi)
            #pragma unroll
            for (int ni = 0; ni < 4; ++ni)
                acc[mi][ni] = __builtin_amdgcn_mfma_f32_16x16x32_bf16(
                    af[mi], bf[ni], acc[mi][ni], 0, 0, 0);
        __syncthreads();
    }

    // epilogue: D layout col = lane&15, row = (lane>>4)*4 + reg
    const int colbase = n0 + wc * 64 + (lane & 15);
    #pragma unroll
    for (int ni = 0; ni < 4; ++ni) {
        const int col = colbase + ni * 16;
        const float bv = bias[col];
        #pragma unroll
        for (int mi = 0; mi < 4; ++mi) {
            const int row0 = m0 + wr * 64 + mi * 16 + (lane >> 4) * 4;
            #pragma unroll
            for (int r = 0; r < 4; ++r) {
                float v = acc[mi][ni][r] + bv;
                if (EPI == 1) v = gelu_exact(v);
                const size_t idx = (size_t)(row0 + r) * Nn + col;
                if (EPI <= 1) {
                    ((unsigned short*)C)[idx] = f2b(v);
                } else {
                    if (EPI == 3) v += resid[idx];
                    ((float*)C)[idx] = v;
                }
            }
        }
    }
}

// ---------------- rotated = quat_rotate(normalize(kraw_bf16), value) in-place ----------------
__global__ __launch_bounds__(256)
void rotate_k(const unsigned short* __restrict__ kraw, float* __restrict__ v, int nq)
{
    const int i = blockIdx.x * 256 + threadIdx.x;
    if (i >= nq) return;
    const ushort4 qu = reinterpret_cast<const ushort4*>(kraw)[i];
    float4 q = qnorm(make_float4(b2f(qu.x), b2f(qu.y), b2f(qu.z), b2f(qu.w)));
    const float4 val = reinterpret_cast<const float4*>(v)[i];
    const float4 r = qmul(qmul(q, val), qconj(q));
    reinterpret_cast<float4*>(v)[i] = r;
}

// ---------------- blocked cumsum along L ----------------
__global__ __launch_bounds__(256)
void scan_pass1(const float* __restrict__ rot, float* __restrict__ part)
{
    const int g  = blockIdx.x * 256 + threadIdx.x;
    const int d  = g & (D - 1);
    const int ch = (g >> 10) & (NCH - 1);
    const int b  = g >> 16;
    const size_t base = ((size_t)b * L + (size_t)ch * CHL) * D + d;
    float s = 0.f;
    for (int i = 0; i < CHL; ++i) s += rot[base + (size_t)i * D];
    part[g] = s;
}

__global__ __launch_bounds__(256)
void scan_pass2(float* __restrict__ part)
{
    const int g = blockIdx.x * 256 + threadIdx.x;
    const int d = g & (D - 1);
    const int b = g >> 10;
    float run = 0.f;
    for (int c = 0; c < NCH; ++c) {
        const size_t idx = ((size_t)b * NCH + c) * D + d;
        const float t = part[idx];
        part[idx] = run;
        run += t;
    }
}

__global__ __launch_bounds__(256)
void scan_pass3(float* __restrict__ rot, const float* __restrict__ part)
{
    const int g  = blockIdx.x * 256 + threadIdx.x;
    const int d  = g & (D - 1);
    const int ch = (g >> 10) & (NCH - 1);
    const int b  = g >> 16;
    const size_t base = ((size_t)b * L + (size_t)ch * CHL) * D + d;
    float run = part[g];
    for (int i = 0; i < CHL; ++i) {
        const size_t idx = base + (size_t)i * D;
        run += rot[idx];
        rot[idx] = run;
    }
}

// ---------------- retrieve + /sqrt(l+1) + LayerNorm -> bf16 ----------------
__global__ __launch_bounds__(256)
void retrieve_ln_k(const float* __restrict__ mem, const unsigned short* __restrict__ qraw,
                   const float* __restrict__ gamma, const float* __restrict__ beta,
                   unsigned short* __restrict__ out)
{
    const int row = blockIdx.x;            // b*L + l
    const int l   = row & (L - 1);
    const int t   = threadIdx.x;           // quat index 0..255
    const size_t base = (size_t)row * D + t * 4;

    const ushort4 qu = reinterpret_cast<const ushort4*>(qraw)[base >> 2];
    const float4 q = qnorm(make_float4(b2f(qu.x), b2f(qu.y), b2f(qu.z), b2f(qu.w)));
    const float4 m4 = *reinterpret_cast<const float4*>(mem + base);
    float4 r = qmul(qmul(qconj(q), m4), q);

    const float inv = 1.0f / sqrtf((float)(l + 1));
    r.x *= inv; r.y *= inv; r.z *= inv; r.w *= inv;

    float s  = r.x + r.y + r.z + r.w;
    float ss = r.x * r.x + r.y * r.y + r.z * r.z + r.w * r.w;
    #pragma unroll
    for (int off = 32; off > 0; off >>= 1) {
        s  += __shfl_xor(s, off);
        ss += __shfl_xor(ss, off);
    }
    __shared__ float red[2][4];
    const int wid = t >> 6, lane = t & 63;
    if (lane == 0) { red[0][wid] = s; red[1][wid] = ss; }
    __syncthreads();
    const float sum = red[0][0] + red[0][1] + red[0][2] + red[0][3];
    const float ssq = red[1][0] + red[1][1] + red[1][2] + red[1][3];
    const float mu  = sum * (1.0f / (float)D);
    const float var = ssq * (1.0f / (float)D) - mu * mu;
    const float sc  = rsqrtf(var + 1e-5f);

    const float4 g4 = *reinterpret_cast<const float4*>(gamma + t * 4);
    const float4 b4 = *reinterpret_cast<const float4*>(beta  + t * 4);
    ushort4 o;
    o.x = f2b((r.x - mu) * sc * g4.x + b4.x);
    o.y = f2b((r.y - mu) * sc * g4.y + b4.y);
    o.z = f2b((r.z - mu) * sc * g4.z + b4.z);
    o.w = f2b((r.w - mu) * sc * g4.w + b4.w);
    reinterpret_cast<ushort4*>(out)[base >> 2] = o;
}

// ---------------- launch ----------------
extern "C" void kernel_launch(void* const* d_in, const int* in_sizes, int n_in,
                              void* d_out, int out_size, void* d_ws, size_t ws_size,
                              hipStream_t stream)
{
    const float* x     = (const float*)d_in[0];
    const float* Wk1   = (const float*)d_in[1];
    const float* bk1   = (const float*)d_in[2];
    const float* Wk2   = (const float*)d_in[3];
    const float* bk2   = (const float*)d_in[4];
    const float* Wq1   = (const float*)d_in[5];
    const float* bq1   = (const float*)d_in[6];
    const float* Wq2   = (const float*)d_in[7];
    const float* bq2   = (const float*)d_in[8];
    const float* Wv    = (const float*)d_in[9];
    const float* bv    = (const float*)d_in[10];
    const float* gamma = (const float*)d_in[11];
    const float* beta  = (const float*)d_in[12];
    const float* Wo    = (const float*)d_in[13];
    const float* bo    = (const float*)d_in[14];
    float* out = (float*)d_out;

    const size_t TD = (size_t)M * D;        // 16,777,216
    const size_t DD = (size_t)D * D;        // 1,048,576
    unsigned short* xb   = (unsigned short*)d_ws;       // bf16 x       (32 MB)
    unsigned short* hb   = xb + TD;                     // bf16 h / ln  (32 MB)
    unsigned short* qb   = hb + TD;                     // bf16 kraw/qraw (32 MB)
    float*          bufB = (float*)(qb + TD);           // f32 value/rot/mem (64 MB)
    unsigned short* wT   = (unsigned short*)(bufB + TD);// 6 x bf16 W^T (12 MB)
    float*          part = (float*)(wT + 6 * DD);       // scan partials (1 MB)

    unsigned short* wk1 = wT;
    unsigned short* wk2 = wT + DD;
    unsigned short* wv_ = wT + 2 * DD;
    unsigned short* wq1 = wT + 3 * DD;
    unsigned short* wq2 = wT + 4 * DD;
    unsigned short* wo_ = wT + 5 * DD;

    const dim3 blk(256);
    const dim3 tblk(32, 8);
    const dim3 tgrid(D / 32, D / 32);
    const int nwg = (M / 128) * (D / 128);  // 1024
    const int nq  = (int)(TD / 4);          // 4,194,304 quats

    conv_k<<<(int)(TD / 4 / 256), blk, 0, stream>>>(x, xb, (int)(TD / 4));
    wtrans_k<<<tgrid, tblk, 0, stream>>>(Wk1, wk1);
    wtrans_k<<<tgrid, tblk, 0, stream>>>(Wk2, wk2);
    wtrans_k<<<tgrid, tblk, 0, stream>>>(Wv,  wv_);
    wtrans_k<<<tgrid, tblk, 0, stream>>>(Wq1, wq1);
    wtrans_k<<<tgrid, tblk, 0, stream>>>(Wq2, wq2);
    wtrans_k<<<tgrid, tblk, 0, stream>>>(Wo,  wo_);

    // K-path
    gemm_bf16_k<1><<<nwg, blk, 0, stream>>>(xb, wk1, bk1, nullptr, hb,   M, D, D); // hk (gelu)
    gemm_bf16_k<0><<<nwg, blk, 0, stream>>>(hb, wk2, bk2, nullptr, qb,   M, D, D); // kraw
    gemm_bf16_k<2><<<nwg, blk, 0, stream>>>(xb, wv_, bv,  nullptr, bufB, M, D, D); // value (f32)

    rotate_k<<<nq / 256, blk, 0, stream>>>(qb, bufB, nq);                          // rotated (in-place)

    scan_pass1<<<(B * NCH * D) / 256, blk, 0, stream>>>(bufB, part);
    scan_pass2<<<(B * D) / 256,       blk, 0, stream>>>(part);
    scan_pass3<<<(B * NCH * D) / 256, blk, 0, stream>>>(bufB, part);               // memory

    // Q-path
    gemm_bf16_k<1><<<nwg, blk, 0, stream>>>(xb, wq1, bq1, nullptr, hb, M, D, D);   // hq (gelu)
    gemm_bf16_k<0><<<nwg, blk, 0, stream>>>(hb, wq2, bq2, nullptr, qb, M, D, D);   // qraw

    retrieve_ln_k<<<M, blk, 0, stream>>>(bufB, qb, gamma, beta, hb);               // ln -> bf16

    gemm_bf16_k<3><<<nwg, blk, 0, stream>>>(hb, wo_, bo, x, out, M, D, D);         // out = ln@Wo+bo+x
}

// Round 4
// 464.513 us; speedup vs baseline: 5.5235x; 1.1049x over previous
//
#include <hip/hip_runtime.h>
#include <cstddef>
#include <cstdint>

static constexpr int Bb  = 4;
static constexpr int Ll  = 4096;
static constexpr int Dd  = 1024;
static constexpr int Mm  = 16384;     // B*L
static constexpr int KK  = 1024;      // GEMM K (all three GEMMs)
static constexpr int NTK = 32;        // K-tiles of BK=32

typedef __attribute__((ext_vector_type(8))) short short8;   // 8 x bf16
typedef __attribute__((ext_vector_type(4))) float f32x4;

#define AS1C(p) ((const __attribute__((address_space(1))) void*)(p))
#define AS3(p)  ((__attribute__((address_space(3))) void*)(p))

// ---------------- scalar helpers ----------------
__device__ __forceinline__ float b2f(unsigned short u) {
    union { unsigned int i; float f; } c; c.i = ((unsigned int)u) << 16; return c.f;
}
__device__ __forceinline__ unsigned short f2b(float f) {
    union { float f; unsigned int i; } c; c.f = f;
    unsigned int r = c.i + 0x7fffu + ((c.i >> 16) & 1u);
    return (unsigned short)(r >> 16);
}
__device__ __forceinline__ float4 qmul(const float4 a, const float4 b) {
    float4 r;
    r.x = a.x * b.x - a.y * b.y - a.z * b.z - a.w * b.w;
    r.y = a.x * b.y + a.y * b.x + a.z * b.w - a.w * b.z;
    r.z = a.x * b.z - a.y * b.w + a.z * b.x + a.w * b.y;
    r.w = a.x * b.w + a.y * b.z - a.z * b.y + a.w * b.x;
    return r;
}
__device__ __forceinline__ float4 qconj(const float4 a) {
    return make_float4(a.x, -a.y, -a.z, -a.w);
}
__device__ __forceinline__ float4 qnorm(const float4 a) {
    float n = sqrtf(a.x * a.x + a.y * a.y + a.z * a.z + a.w * a.w);
    float inv = 1.0f / fmaxf(n, 1e-12f);
    return make_float4(a.x * inv, a.y * inv, a.z * inv, a.w * inv);
}
// A&S 7.1.26 erf (|eps| <= 1.5e-7), branchless
__device__ __forceinline__ float gelu_fast(float v) {
    const float a = fabsf(v) * 0.70710678118654752f;
    const float t = 1.0f / (1.0f + 0.3275911f * a);
    const float p = t * (0.254829592f + t * (-0.284496736f + t * (1.421413741f
                   + t * (-1.453152027f + t * 1.061405429f))));
    const float e = __expf(-a * a);
    const float erfa = 1.0f - p * e;                 // erf(|x|)
    const float erfv = copysignf(erfa, v);
    return 0.5f * v * (1.0f + erfv);
}

// ---------------- fp32 -> bf16 convert ----------------
__global__ __launch_bounds__(256)
void conv_k(const float* __restrict__ src, unsigned short* __restrict__ dst, int n4)
{
    const int i = blockIdx.x * 256 + threadIdx.x;
    if (i >= n4) return;
    const float4 v = reinterpret_cast<const float4*>(src)[i];
    ushort4 o;
    o.x = f2b(v.x); o.y = f2b(v.y); o.z = f2b(v.z); o.w = f2b(v.w);
    reinterpret_cast<ushort4*>(dst)[i] = o;
}

// ---------------- W[K,N] fp32 -> W^T[N,K] bf16 ----------------
__global__ __launch_bounds__(256)
void wtrans_k(const float* __restrict__ src, unsigned short* __restrict__ dst)
{
    __shared__ float t[32][33];
    const int tx = threadIdx.x, ty = threadIdx.y;       // 32 x 8
    const int n0 = blockIdx.x * 32, k0 = blockIdx.y * 32;
    #pragma unroll
    for (int j = ty; j < 32; j += 8)
        t[j][tx] = src[(size_t)(k0 + j) * Dd + n0 + tx];
    __syncthreads();
    #pragma unroll
    for (int j = ty; j < 32; j += 8)
        dst[(size_t)(n0 + j) * Dd + k0 + tx] = f2b(t[tx][j]);
}

// ---------------- bias concat ----------------
__global__ __launch_bounds__(256)
void bcat_k(const float* __restrict__ bk1, const float* __restrict__ bq1,
            const float* __restrict__ bv,  const float* __restrict__ bk2,
            const float* __restrict__ bq2, float* __restrict__ b1,
            float* __restrict__ b2)
{
    const int i = blockIdx.x * 256 + threadIdx.x;
    if (i < 3072) b1[i] = (i < 1024) ? bk1[i] : (i < 2048 ? bq1[i - 1024] : bv[i - 2048]);
    if (i < 2048) b2[i] = (i < 1024) ? bk2[i] : bq2[i - 1024];
}

// ---------------- 256x256 pipelined MFMA GEMM (BK=32, 3-buf, depth-2 prefetch) ----
// MODE 0: A=xb[M,1024], BT=wcat1[3072,1024] -> cols<2048: gelu->bf16 outH[M,2048];
//                                              cols>=2048: f32 outF[M,1024] (value)
// MODE 1: A=h[M,2048] (block-diag: aoff=1024 for n0>=1024), BT=wcat2[2048,1024]
//         -> bf16 outH[M,2048]
// MODE 2: A=ln[M,1024], BT=woT -> f32 outF = acc+bias+resid
template<int MODE>
__global__ __launch_bounds__(512, 2)
void gemm256_k(const unsigned short* __restrict__ A, int astride,
               const unsigned short* __restrict__ BT,
               const float* __restrict__ bias,
               const float* __restrict__ resid,
               unsigned short* __restrict__ outH,
               float* __restrict__ outF,
               int Nn)
{
    extern __shared__ char smem[];   // 96 KB: A bufs @ 0,16K,32K ; B bufs @ 48K,64K,80K
    const int tid  = threadIdx.x;
    const int lane = tid & 63;
    const int w    = tid >> 6;       // 0..7
    const int wr   = w >> 2;         // 0..1 -> A half (rows)
    const int wc   = w & 3;          // 0..3 -> B quarter (cols)

    // XCD-aware bijective swizzle (gridDim.x % 8 == 0 for all our grids)
    const int nwg = gridDim.x;
    const int cpx = nwg >> 3;
    const int bid = blockIdx.x;
    const int swz = (bid & 7) * cpx + (bid >> 3);
    const int nTN = Nn >> 8;
    const int m0  = (swz / nTN) << 8;
    const int n0  = (swz % nTN) << 8;
    const int aoff = (MODE == 1 && n0 >= 1024) ? 1024 : 0;

    // ---- staging source precompute ----
    // linear 16B slot n16 = c*512 + tid ; line=n16>>3 ; s=n16&7 ; u=s^(line&7)
    // unswizzled (r,kc): r=2*line+(u>>2), kc=u&3  => LDS holds swizzled layout
    const unsigned short* gA[2];
    const unsigned short* gB[2];
    #pragma unroll
    for (int c = 0; c < 2; ++c) {
        const int n16 = c * 512 + tid;
        const int line = n16 >> 3;
        const int u = (n16 & 7) ^ (line & 7);
        const int r = 2 * line + (u >> 2);
        const int kcs = u & 3;
        gA[c] = A + (size_t)(m0 + r) * astride + aoff + kcs * 8;
        gB[c] = BT + (size_t)(n0 + r) * KK + kcs * 8;
    }
    const int wslot = w * 1024;   // byte offset of this wave's 64 lanes within an 8KB chunk

    auto STAGE = [&](int kt, int bi) {
        const int koff = kt * 32;
        #pragma unroll
        for (int c = 0; c < 2; ++c) {
            __builtin_amdgcn_global_load_lds(AS1C(gA[c] + koff),
                AS3(smem + bi * 16384 + c * 8192 + wslot), 16, 0, 0);
            __builtin_amdgcn_global_load_lds(AS1C(gB[c] + koff),
                AS3(smem + 49152 + bi * 16384 + c * 8192 + wslot), 16, 0, 0);
        }
    };

    // ---- fragment read offsets (loop-invariant, swizzled) ----
    const int kc = lane >> 4;       // k-chunk 0..3 (8 elems each)
    const int rl = lane & 15;
    int offA[8], offB[4];
    #pragma unroll
    for (int mi = 0; mi < 8; ++mi) {
        const int r = wr * 128 + mi * 16 + rl;
        offA[mi] = (r >> 1) * 128 + (((((r & 1) << 2) | kc) ^ ((r >> 1) & 7)) << 4);
    }
    #pragma unroll
    for (int ni = 0; ni < 4; ++ni) {
        const int r = wc * 64 + ni * 16 + rl;
        offB[ni] = 49152 + (r >> 1) * 128 + (((((r & 1) << 2) | kc) ^ ((r >> 1) & 7)) << 4);
    }

    f32x4 acc[8][4] = {};

    auto BODY = [&](int kt, int bi, int bi2, int vm, bool dostage) {
        if (dostage) STAGE(kt + 2, bi2);
        const char* Ab = smem + bi * 16384;
        short8 af[4], bf[4];
        #pragma unroll
        for (int ni = 0; ni < 4; ++ni) bf[ni] = *(const short8*)(smem + bi * 16384 + offB[ni]);
        #pragma unroll
        for (int mi = 0; mi < 4; ++mi) af[mi] = *(const short8*)(Ab + offA[mi]);
        __builtin_amdgcn_s_barrier();
        __builtin_amdgcn_s_setprio(1);
        #pragma unroll
        for (int mi = 0; mi < 4; ++mi)
            #pragma unroll
            for (int ni = 0; ni < 4; ++ni)
                acc[mi][ni] = __builtin_amdgcn_mfma_f32_16x16x32_bf16(af[mi], bf[ni], acc[mi][ni], 0, 0, 0);
        __builtin_amdgcn_s_setprio(0);
        __builtin_amdgcn_s_barrier();
        #pragma unroll
        for (int mi = 0; mi < 4; ++mi) af[mi] = *(const short8*)(Ab + offA[4 + mi]);
        __builtin_amdgcn_s_setprio(1);
        #pragma unroll
        for (int mi = 0; mi < 4; ++mi)
            #pragma unroll
            for (int ni = 0; ni < 4; ++ni)
                acc[4 + mi][ni] = __builtin_amdgcn_mfma_f32_16x16x32_bf16(af[mi], bf[ni], acc[4 + mi][ni], 0, 0, 0);
        __builtin_amdgcn_s_setprio(0);
        if (vm == 4)      asm volatile("s_waitcnt vmcnt(4)" ::: "memory");
        else if (vm == 0) asm volatile("s_waitcnt vmcnt(0)" ::: "memory");
        if (vm >= 0) __builtin_amdgcn_s_barrier();
    };

    // prologue: stage tiles 0,1 ; ensure tile0 resident
    STAGE(0, 0);
    STAGE(1, 1);
    asm volatile("s_waitcnt vmcnt(4)" ::: "memory");
    __builtin_amdgcn_s_barrier();

    // main loop: 30 iters (unroll-by-3 so buffer ids are static), then 2 peeled
    for (int t0 = 0; t0 < NTK - 2; t0 += 3) {
        BODY(t0 + 0, 0, 2, 4, true);
        BODY(t0 + 1, 1, 0, 4, true);
        BODY(t0 + 2, 2, 1, 4, true);
    }
    BODY(NTK - 2, 0, 0, 0, false);   // vmcnt(0): drain last tile
    BODY(NTK - 1, 1, 0, -1, false);

    // ---- epilogue: C layout col = lane&15 (+16*ni), row = (lane>>4)*4 + reg ----
    const int colb = n0 + wc * 64 + rl;
    const int rowb = m0 + wr * 128 + kc * 4;
    #pragma unroll
    for (int ni = 0; ni < 4; ++ni) {
        const int col = colb + ni * 16;
        const float bv = bias[col];
        #pragma unroll
        for (int mi = 0; mi < 8; ++mi) {
            const int row0 = rowb + mi * 16;
            #pragma unroll
            for (int rr = 0; rr < 4; ++rr) {
                float v = acc[mi][ni][rr] + bv;
                const int row = row0 + rr;
                if (MODE == 0) {
                    if (n0 < 2048) outH[(size_t)row * 2048 + col] = f2b(gelu_fast(v));
                    else           outF[(size_t)row * 1024 + (col - 2048)] = v;
                } else if (MODE == 1) {
                    outH[(size_t)row * 2048 + col] = f2b(v);
                } else {
                    const size_t ix = (size_t)row * 1024 + col;
                    outF[ix] = v + resid[ix];
                }
            }
        }
    }
}

// ---------------- rotate (normalize(kraw) rot value) + chunk-sum (scan pass 1) ----
__global__ __launch_bounds__(256)
void rotfuse_k(const unsigned short* __restrict__ qb2, float* __restrict__ val,
               float* __restrict__ part)
{
    const int idx = blockIdx.x * 256 + threadIdx.x;   // 0..65535 : (b, ch, kq)
    const int kq  = idx & 255;
    const int ch  = (idx >> 8) & 63;
    const int b   = idx >> 14;
    const int row0 = b * Ll + ch * 64;
    float4 s = make_float4(0.f, 0.f, 0.f, 0.f);
    for (int i = 0; i < 64; ++i) {
        const int row = row0 + i;
        const ushort4 qu = *reinterpret_cast<const ushort4*>(qb2 + (size_t)row * 2048 + kq * 4);
        const float4 q = qnorm(make_float4(b2f(qu.x), b2f(qu.y), b2f(qu.z), b2f(qu.w)));
        float4* vp = reinterpret_cast<float4*>(val + (size_t)row * 1024 + kq * 4);
        const float4 r = qmul(qmul(q, *vp), qconj(q));
        *vp = r;
        s.x += r.x; s.y += r.y; s.z += r.z; s.w += r.w;
    }
    *reinterpret_cast<float4*>(part + (size_t)idx * 4) = s;
}

// ---------------- scan pass 2: exclusive scan of chunk sums ----------------
__global__ __launch_bounds__(256)
void scan2_k(float* __restrict__ part)
{
    const int idx = blockIdx.x * 256 + threadIdx.x;   // 0..1023 : (b, kq)
    const int kq = idx & 255, b = idx >> 8;
    float4 run = make_float4(0.f, 0.f, 0.f, 0.f);
    for (int c = 0; c < 64; ++c) {
        float4* p = reinterpret_cast<float4*>(part + (((size_t)(b * 64 + c)) * 256 + kq) * 4);
        const float4 t = *p;
        *p = run;
        run.x += t.x; run.y += t.y; run.z += t.z; run.w += t.w;
    }
}

// ---------------- scan pass 3: in-place cumsum ----------------
__global__ __launch_bounds__(256)
void scan3_k(float* __restrict__ val, const float* __restrict__ part)
{
    const int idx = blockIdx.x * 256 + threadIdx.x;
    const int kq  = idx & 255;
    const int ch  = (idx >> 8) & 63;
    const int b   = idx >> 14;
    const int row0 = b * Ll + ch * 64;
    float4 run = *reinterpret_cast<const float4*>(part + (size_t)idx * 4);
    for (int i = 0; i < 64; ++i) {
        float4* vp = reinterpret_cast<float4*>(val + (size_t)(row0 + i) * 1024 + kq * 4);
        const float4 v = *vp;
        run.x += v.x; run.y += v.y; run.z += v.z; run.w += v.w;
        *vp = run;
    }
}

// ---------------- retrieve + /sqrt(l+1) + LayerNorm -> bf16 ----------------
__global__ __launch_bounds__(256)
void retrieve_ln_k(const float* __restrict__ mem, const unsigned short* __restrict__ qb2,
                   const float* __restrict__ gamma, const float* __restrict__ beta,
                   unsigned short* __restrict__ out)
{
    const int row = blockIdx.x;            // b*L + l
    const int l   = row & (Ll - 1);
    const int t   = threadIdx.x;           // quat index 0..255
    const size_t base = (size_t)row * 1024 + t * 4;

    const ushort4 qu = *reinterpret_cast<const ushort4*>(qb2 + (size_t)row * 2048 + 1024 + t * 4);
    const float4 q = qnorm(make_float4(b2f(qu.x), b2f(qu.y), b2f(qu.z), b2f(qu.w)));
    const float4 m4 = *reinterpret_cast<const float4*>(mem + base);
    float4 r = qmul(qmul(qconj(q), m4), q);

    const float inv = 1.0f / sqrtf((float)(l + 1));
    r.x *= inv; r.y *= inv; r.z *= inv; r.w *= inv;

    float s  = r.x + r.y + r.z + r.w;
    float ss = r.x * r.x + r.y * r.y + r.z * r.z + r.w * r.w;
    #pragma unroll
    for (int off = 32; off > 0; off >>= 1) {
        s  += __shfl_xor(s, off);
        ss += __shfl_xor(ss, off);
    }
    __shared__ float red[2][4];
    const int wid = t >> 6, lane = t & 63;
    if (lane == 0) { red[0][wid] = s; red[1][wid] = ss; }
    __syncthreads();
    const float sum = red[0][0] + red[0][1] + red[0][2] + red[0][3];
    const float ssq = red[1][0] + red[1][1] + red[1][2] + red[1][3];
    const float mu  = sum * (1.0f / 1024.0f);
    const float var = ssq * (1.0f / 1024.0f) - mu * mu;
    const float sc  = rsqrtf(var + 1e-5f);

    const float4 g4 = *reinterpret_cast<const float4*>(gamma + t * 4);
    const float4 b4 = *reinterpret_cast<const float4*>(beta  + t * 4);
    ushort4 o;
    o.x = f2b((r.x - mu) * sc * g4.x + b4.x);
    o.y = f2b((r.y - mu) * sc * g4.y + b4.y);
    o.z = f2b((r.z - mu) * sc * g4.z + b4.z);
    o.w = f2b((r.w - mu) * sc * g4.w + b4.w);
    *reinterpret_cast<ushort4*>(out + base) = o;
}

// ---------------- launch ----------------
extern "C" void kernel_launch(void* const* d_in, const int* in_sizes, int n_in,
                              void* d_out, int out_size, void* d_ws, size_t ws_size,
                              hipStream_t stream)
{
    const float* x     = (const float*)d_in[0];
    const float* Wk1   = (const float*)d_in[1];
    const float* bk1   = (const float*)d_in[2];
    const float* Wk2   = (const float*)d_in[3];
    const float* bk2   = (const float*)d_in[4];
    const float* Wq1   = (const float*)d_in[5];
    const float* bq1   = (const float*)d_in[6];
    const float* Wq2   = (const float*)d_in[7];
    const float* bq2   = (const float*)d_in[8];
    const float* Wv    = (const float*)d_in[9];
    const float* bv    = (const float*)d_in[10];
    const float* gamma = (const float*)d_in[11];
    const float* beta  = (const float*)d_in[12];
    const float* Wo    = (const float*)d_in[13];
    const float* bo    = (const float*)d_in[14];
    float* out = (float*)d_out;

    const size_t TD = (size_t)Mm * 1024;     // 16,777,216
    const size_t DD = (size_t)1024 * 1024;

    // memory map (~199 MB):
    // qb2 [M,2048] bf16 (64MB) -- first 32MB doubles as xb, next 6MB as wcat1
    unsigned short* qb2   = (unsigned short*)d_ws;
    unsigned short* xb    = qb2;                    // [M,1024] bf16 (dead before qb2 written)
    unsigned short* wcat1 = qb2 + TD;               // [3072,1024] bf16 (dead before qb2 written)
    unsigned short* h     = qb2 + 2 * TD;           // [M,2048] bf16 (64MB); ln reuses first half
    float*          bufB  = (float*)(h + 2 * TD);   // [M,1024] f32 (64MB) value/rot/mem
    unsigned short* wcat2 = (unsigned short*)(bufB + TD);  // [2048,1024] bf16 (4MB)
    unsigned short* woT   = wcat2 + 2 * DD;         // [1024,1024] bf16 (2MB)
    float*          bcat1 = (float*)(woT + DD);     // 3072
    float*          bcat2 = bcat1 + 3072;           // 2048
    float*          part  = bcat2 + 2048;           // B*64*256*4 = 262144 f32 (1MB)

    const dim3 blk(256);
    const dim3 tblk(32, 8);
    const dim3 tgrid(32, 32);

    // allow 96KB dynamic LDS on the gemm kernels (host-side attribute, capture-safe)
    (void)hipFuncSetAttribute((const void*)gemm256_k<0>, hipFuncAttributeMaxDynamicSharedMemorySize, 98304);
    (void)hipFuncSetAttribute((const void*)gemm256_k<1>, hipFuncAttributeMaxDynamicSharedMemorySize, 98304);
    (void)hipFuncSetAttribute((const void*)gemm256_k<2>, hipFuncAttributeMaxDynamicSharedMemorySize, 98304);

    conv_k<<<(int)(TD / 4 / 256), blk, 0, stream>>>(x, xb, (int)(TD / 4));
    wtrans_k<<<tgrid, tblk, 0, stream>>>(Wk1, wcat1);
    wtrans_k<<<tgrid, tblk, 0, stream>>>(Wq1, wcat1 + DD);
    wtrans_k<<<tgrid, tblk, 0, stream>>>(Wv,  wcat1 + 2 * DD);
    wtrans_k<<<tgrid, tblk, 0, stream>>>(Wk2, wcat2);
    wtrans_k<<<tgrid, tblk, 0, stream>>>(Wq2, wcat2 + DD);
    wtrans_k<<<tgrid, tblk, 0, stream>>>(Wo,  woT);
    bcat_k<<<12, blk, 0, stream>>>(bk1, bq1, bv, bk2, bq2, bcat1, bcat2);

    // GEMM-A: x @ [Wk1|Wq1|Wv]  (N=3072) -> h (gelu bf16, cols<2048), bufB (f32 value)
    gemm256_k<0><<<64 * 12, 512, 98304, stream>>>(xb, 1024, wcat1, bcat1, nullptr, h, bufB, 3072);
    // GEMM-B: block-diag h @ {Wk2,Wq2} (N=2048) -> qb2 = [kraw|qraw] bf16
    gemm256_k<1><<<64 * 8, 512, 98304, stream>>>(h, 2048, wcat2, bcat2, nullptr, qb2, nullptr, 2048);

    rotfuse_k<<<256, blk, 0, stream>>>(qb2, bufB, part);   // rotate + chunk sums
    scan2_k<<<4, blk, 0, stream>>>(part);
    scan3_k<<<256, blk, 0, stream>>>(bufB, part);          // bufB = memory

    retrieve_ln_k<<<Mm, blk, 0, stream>>>(bufB, qb2, gamma, beta, h);  // ln -> h[M,1024]

    // GEMM-C: ln @ Wo + bo + x -> out (f32)
    gemm256_k<2><<<64 * 4, 512, 98304, stream>>>(h, 1024, woT, bo, x, nullptr, out, 1024);
}